// Round 11
// baseline (679.062 us; speedup 1.0000x reference)
//
#include <hip/hip_runtime.h>
#include <hip/hip_bf16.h>
#include <math.h>

#define NN 100000
#define CC 128
#define EE 1600000
#define SCAN_CHUNK 2048
#define NB_SCAN ((NN + SCAN_CHUNK - 1) / SCAN_CHUNK)  // 49
#define NRANGE 8
#define RNODES (NN / NRANGE)     // 12500
#define EPT 8                    // edges per thread in partitioned edge kernels
#define FCHUNK (256 * EPT)       // 2048 edges per block
#define NCHUNKS ((EE + FCHUNK - 1) / FCHUNK)  // 782

typedef short  bf16x8 __attribute__((ext_vector_type(8)));
typedef float  f32x4  __attribute__((ext_vector_type(4)));
typedef float  f32x4v __attribute__((ext_vector_type(4)));
typedef unsigned short u16x8 __attribute__((ext_vector_type(8)));

#define APAD 136   // ushort stride for per-wave A tiles (272 B)
#define TPAD 132   // float stride for per-wave T tiles (528 B)

__device__ __forceinline__ ushort f2bf(float f) {
    __hip_bfloat16 h = __float2bfloat16(f);   // RNE
    return __builtin_bit_cast(ushort, h);
}
__device__ __forceinline__ float bf2f(ushort u) {
    return __builtin_bit_cast(float, ((unsigned int)u) << 16);
}

// ===========================================================================
// CSR build — R7's exact measured-best forms (EPT=8, plain loads,
// conditional scalar src). fill is atomic-chain-bound at ~20G chains/s.
// ===========================================================================
__global__ void __launch_bounds__(256) hist_part(
    const int* __restrict__ dst, int* __restrict__ deg)
{
    int range = blockIdx.x & (NRANGE - 1);
    int chunk = blockIdx.x >> 3;
    int lo = range * RNODES, hi = lo + RNODES;
    int base = chunk * FCHUNK + threadIdx.x * EPT;
    if (base + EPT <= EE) {
        int4 d0 = *(const int4*)&dst[base];
        int4 d1 = *(const int4*)&dst[base + 4];
        int dd[8] = {d0.x, d0.y, d0.z, d0.w, d1.x, d1.y, d1.z, d1.w};
#pragma unroll
        for (int i = 0; i < 8; ++i) {
            int d = dd[i];
            if (d >= lo && d < hi) atomicAdd(&deg[d], 1);
        }
    } else {
        for (int i = 0; i < EPT; ++i) {
            int e = base + i;
            if (e < EE) {
                int d = dst[e];
                if (d >= lo && d < hi) atomicAdd(&deg[d], 1);
            }
        }
    }
}

__global__ void __launch_bounds__(256) deg_block_reduce(
    const int* __restrict__ deg, int* __restrict__ blockSums)
{
    int base = blockIdx.x * SCAN_CHUNK + threadIdx.x * 8;
    int s = 0;
#pragma unroll
    for (int i = 0; i < 8; ++i) {
        int idx = base + i;
        if (idx < NN) s += deg[idx];
    }
#pragma unroll
    for (int off = 32; off > 0; off >>= 1) s += __shfl_down(s, off);
    __shared__ int ws[4];
    int lane = threadIdx.x & 63, wid = threadIdx.x >> 6;
    if (lane == 0) ws[wid] = s;
    __syncthreads();
    if (threadIdx.x == 0) blockSums[blockIdx.x] = ws[0] + ws[1] + ws[2] + ws[3];
}

__global__ void scan_offsets(const int* __restrict__ blockSums,
                             int* __restrict__ blockOff, int* __restrict__ rowptr)
{
    int lane = threadIdx.x;  // 64 threads
    int v = (lane < NB_SCAN) ? blockSums[lane] : 0;
    int inc = v;
#pragma unroll
    for (int off = 1; off < 64; off <<= 1) {
        int n = __shfl_up(inc, off);
        if (lane >= off) inc += n;
    }
    if (lane < NB_SCAN) blockOff[lane] = inc - v;
    if (lane == 63) rowptr[NN] = EE;
}

__global__ void __launch_bounds__(256) deg_scan_write(
    const int* __restrict__ deg, const int* __restrict__ blockOff,
    int* __restrict__ rowptr, int* __restrict__ cursor)
{
    __shared__ int warpSums[4];
    int base = blockIdx.x * SCAN_CHUNK + threadIdx.x * 8;
    int v[8];
    int s = 0;
#pragma unroll
    for (int i = 0; i < 8; ++i) {
        int idx = base + i;
        v[i] = (idx < NN) ? deg[idx] : 0;
        s += v[i];
    }
    int lane = threadIdx.x & 63, wid = threadIdx.x >> 6;
    int inc = s;
#pragma unroll
    for (int off = 1; off < 64; off <<= 1) {
        int n = __shfl_up(inc, off);
        if (lane >= off) inc += n;
    }
    if (lane == 63) warpSums[wid] = inc;
    __syncthreads();
    int wofs = 0;
#pragma unroll
    for (int w = 0; w < 4; ++w)
        if (w < wid) wofs += warpSums[w];
    int exc = blockOff[blockIdx.x] + wofs + (inc - s);
#pragma unroll
    for (int i = 0; i < 8; ++i) {
        int idx = base + i;
        if (idx < NN) { rowptr[idx] = exc; cursor[idx] = exc; }
        exc += v[i];
    }
}

__global__ void __launch_bounds__(256) fill_csr_part(
    const int* __restrict__ src, const int* __restrict__ dst,
    int* __restrict__ cursor, int* __restrict__ col)
{
    int range = blockIdx.x & (NRANGE - 1);
    int chunk = blockIdx.x >> 3;
    int lo = range * RNODES, hi = lo + RNODES;
    int base = chunk * FCHUNK + threadIdx.x * EPT;
    if (base + EPT <= EE) {
        int4 d0 = *(const int4*)&dst[base];
        int4 d1 = *(const int4*)&dst[base + 4];
        int dd[8] = {d0.x, d0.y, d0.z, d0.w, d1.x, d1.y, d1.z, d1.w};
#pragma unroll
        for (int i = 0; i < 8; ++i) {
            int d = dd[i];
            if (d >= lo && d < hi) {
                int s = src[base + i];
                int pos = atomicAdd(&cursor[d], 1);
                col[pos] = s;
            }
        }
    } else {
        for (int i = 0; i < EPT; ++i) {
            int e = base + i;
            if (e < EE) {
                int d = dst[e];
                if (d >= lo && d < hi) {
                    int s = src[e];
                    int pos = atomicAdd(&cursor[d], 1);
                    col[pos] = s;
                }
            }
        }
    }
}

// ===========================================================================
// Conversions
// ===========================================================================
__global__ void __launch_bounds__(256) convert_x_kernel(
    const float* __restrict__ x, ushort* __restrict__ xb)
{
    int i = blockIdx.x * 256 + threadIdx.x;   // float4 groups; NN*CC/4 total
    f32x4v v = __builtin_nontemporal_load((const f32x4v*)x + i);  // single-use stream
    ushort4 o;
    o.x = f2bf(v[0]); o.y = f2bf(v[1]); o.z = f2bf(v[2]); o.w = f2bf(v[3]);
    ((ushort4*)xb)[i] = o;
}

__global__ void __launch_bounds__(256) convert_w6_kernel(
    const float* __restrict__ w0, const float* __restrict__ w1,
    const float* __restrict__ w2, const float* __restrict__ w3,
    const float* __restrict__ w4, const float* __restrict__ w5,
    ushort* __restrict__ wt)
{
    int i = blockIdx.x * 256 + threadIdx.x;  // 6*16384
    int mat = i >> 14;
    int rem = i & 16383;
    int k = rem >> 7, n = rem & 127;
    const float* w = (mat == 0) ? w0 : (mat == 1) ? w1 : (mat == 2) ? w2
                   : (mat == 3) ? w3 : (mat == 4) ? w4 : w5;
    wt[mat * 16384 + n * 128 + k] = f2bf(w[k * 128 + n]);
}

// ===========================================================================
// Fused barrier-free GIN layer, per-wave: each wave owns 16 rows end-to-end.
//   gather (shfl-broadcast cols, unroll-4 row loads) -> LDS A tile ->
//   MFMA stage1 -> per-wave T -> MFMA stage2 -> store (or fused head).
// NO __syncthreads anywhere: 16 waves/CU flow through phases independently,
// so gather-phase loads of some waves cover MFMA/weight-load stalls of others.
// LDS per wave: union of A tile (bf16, 4.3 KB) and T tile (fp32, 8.4 KB).
// ===========================================================================
template <bool FUSE_HEAD>
__global__ void __launch_bounds__(256) gin_wave(
    const ushort* __restrict__ hin, const int* __restrict__ rowptr,
    const int* __restrict__ col,
    const ushort* __restrict__ waT, const float* __restrict__ ba,
    const ushort* __restrict__ wbT, const float* __restrict__ bb,
    ushort* __restrict__ hout,
    const float* __restrict__ lw, const float* __restrict__ lb,
    float* __restrict__ out)
{
    __shared__ float smem[4][16 * TPAD];   // 33792 B -> 4 blocks/CU

    const int wave = threadIdx.x >> 6;
    const int lane = threadIdx.x & 63;
    const int quad = lane >> 4;
    const int l16  = lane & 15;
    const int wv   = blockIdx.x * 4 + wave;
    const int wrow0 = wv * 16;             // NN % 16 == 0
    if (wrow0 >= NN) return;
    float*  T  = smem[wave];
    ushort* At = (ushort*)T;               // union: At dies before T written

    // ---- fused gather into At: group quad handles rows quad*4..quad*4+3 ----
    {
        const int gbase = lane & 48;       // group base lane within wave
        const u16x8* hp = (const u16x8*)hin;
#pragma unroll
        for (int i = 0; i < 4; ++i) {
            int r = quad * 4 + i;
            int n = wrow0 + r;
            u16x8 self = hp[n * 16 + l16];
            float s0[8], s1[8], s2[8], s3[8];
#pragma unroll
            for (int k = 0; k < 8; ++k) {
                s0[k] = bf2f(self[k]); s1[k] = 0.f; s2[k] = 0.f; s3[k] = 0.f;
            }
            int beg = rowptr[n], end = rowptr[n + 1];
            while (beg < end) {
                int take = end - beg;
                if (take > 16) take = 16;
                int ci = (l16 < take) ? col[beg + l16] : 0;
                int j = 0;
                for (; j + 4 <= take; j += 4) {
                    int n0 = __shfl(ci, gbase + j + 0);
                    int n1 = __shfl(ci, gbase + j + 1);
                    int n2 = __shfl(ci, gbase + j + 2);
                    int n3 = __shfl(ci, gbase + j + 3);
                    u16x8 a0 = hp[n0 * 16 + l16];
                    u16x8 a1 = hp[n1 * 16 + l16];
                    u16x8 a2 = hp[n2 * 16 + l16];
                    u16x8 a3 = hp[n3 * 16 + l16];
#pragma unroll
                    for (int k = 0; k < 8; ++k) {
                        s0[k] += bf2f(a0[k]); s1[k] += bf2f(a1[k]);
                        s2[k] += bf2f(a2[k]); s3[k] += bf2f(a3[k]);
                    }
                }
                for (; j < take; ++j) {
                    int n0 = __shfl(ci, gbase + j);
                    u16x8 a0 = hp[n0 * 16 + l16];
#pragma unroll
                    for (int k = 0; k < 8; ++k) s0[k] += bf2f(a0[k]);
                }
                beg += take;
            }
            bf16x8 o;
#pragma unroll
            for (int k = 0; k < 8; ++k) o[k] = (short)f2bf(s0[k] + s1[k] + s2[k] + s3[k]);
            *(bf16x8*)&At[r * APAD + l16 * 8] = o;
        }
    }
    // within-wave LDS write->read: in-order LDS pipe + compiler lgkmcnt

    // ---- stage-1 A fragments (row = l16, k-chunk = kk*32 + quad*8) ----
    bf16x8 afrag[4];
#pragma unroll
    for (int kk = 0; kk < 4; ++kk)
        afrag[kk] = *(const bf16x8*)&At[l16 * APAD + kk * 32 + quad * 8];

    // ---- stage 1: T = relu(A @ Wa + ba) ----
    f32x4 acc[8];
#pragma unroll
    for (int nt = 0; nt < 8; ++nt) acc[nt] = (f32x4){0.f, 0.f, 0.f, 0.f};
#pragma unroll
    for (int kk = 0; kk < 4; ++kk) {
#pragma unroll
        for (int nt = 0; nt < 8; ++nt) {
            bf16x8 bfrag = *(const bf16x8*)&waT[(nt * 16 + l16) * CC + kk * 32 + quad * 8];
            acc[nt] = __builtin_amdgcn_mfma_f32_16x16x32_bf16(afrag[kk], bfrag, acc[nt], 0, 0, 0);
        }
    }
#pragma unroll
    for (int nt = 0; nt < 8; ++nt) {
        int colc = nt * 16 + l16;
        float bias = ba[colc];
#pragma unroll
        for (int r = 0; r < 4; ++r) {
            float v = acc[nt][r] + bias;
            T[(quad * 4 + r) * TPAD + colc] = fmaxf(v, 0.f);
        }
    }

    // ---- stage-2 A fragments from T (cvt fp32 -> bf16) ----
    bf16x8 a2[4];
#pragma unroll
    for (int kk = 0; kk < 4; ++kk) {
        const float* tp = &T[l16 * TPAD + kk * 32 + quad * 8];
        float4 t0 = *(const float4*)tp;
        float4 t1 = *(const float4*)(tp + 4);
        bf16x8 f;
        f[0] = (short)f2bf(t0.x); f[1] = (short)f2bf(t0.y);
        f[2] = (short)f2bf(t0.z); f[3] = (short)f2bf(t0.w);
        f[4] = (short)f2bf(t1.x); f[5] = (short)f2bf(t1.y);
        f[6] = (short)f2bf(t1.z); f[7] = (short)f2bf(t1.w);
        a2[kk] = f;
    }

    // ---- stage 2: out = elu(T @ Wb + bb) ----
    f32x4 acc2[8];
#pragma unroll
    for (int nt = 0; nt < 8; ++nt) acc2[nt] = (f32x4){0.f, 0.f, 0.f, 0.f};
#pragma unroll
    for (int kk = 0; kk < 4; ++kk) {
#pragma unroll
        for (int nt = 0; nt < 8; ++nt) {
            bf16x8 bfrag = *(const bf16x8*)&wbT[(nt * 16 + l16) * CC + kk * 32 + quad * 8];
            acc2[nt] = __builtin_amdgcn_mfma_f32_16x16x32_bf16(a2[kk], bfrag, acc2[nt], 0, 0, 0);
        }
    }

    if (FUSE_HEAD) {
        float part[4] = {0.f, 0.f, 0.f, 0.f};
#pragma unroll
        for (int nt = 0; nt < 8; ++nt) {
            int colc = nt * 16 + l16;
            float bias = bb[colc];
            float w = lw[colc];
#pragma unroll
            for (int r = 0; r < 4; ++r) {
                float v = acc2[nt][r] + bias;
                v = v > 0.f ? v : expm1f(v);
                part[r] += v * w;
            }
        }
#pragma unroll
        for (int r = 0; r < 4; ++r) {
#pragma unroll
            for (int off = 8; off > 0; off >>= 1)
                part[r] += __shfl_xor(part[r], off);
        }
        if (l16 == 0) {
            float lbv = lb[0];
#pragma unroll
            for (int r = 0; r < 4; ++r) {
                int grow = wrow0 + quad * 4 + r;
                float z = part[r] + lbv;
                out[grow] = 1.f / (1.f + expf(-z));
            }
        }
    } else {
        // elu -> T (safe: same-wave a2 reads already returned) -> bf16 store
#pragma unroll
        for (int nt = 0; nt < 8; ++nt) {
            int colc = nt * 16 + l16;
            float bias = bb[colc];
#pragma unroll
            for (int r = 0; r < 4; ++r) {
                float v = acc2[nt][r] + bias;
                T[(quad * 4 + r) * TPAD + colc] = v > 0.f ? v : expm1f(v);
            }
        }
#pragma unroll
        for (int i = 0; i < 4; ++i) {
            int r  = i * 4 + quad;           // 0..15
            int cv = l16;                    // 16B chunk (8 values)
            const float* tp = &T[r * TPAD + cv * 8];
            float4 t0 = *(const float4*)tp;
            float4 t1 = *(const float4*)(tp + 4);
            ushort4 o0, o1;
            o0.x = f2bf(t0.x); o0.y = f2bf(t0.y); o0.z = f2bf(t0.z); o0.w = f2bf(t0.w);
            o1.x = f2bf(t1.x); o1.y = f2bf(t1.y); o1.z = f2bf(t1.z); o1.w = f2bf(t1.w);
            ushort* dstp = &hout[(wrow0 + r) * CC + cv * 8];
            *(ushort4*)dstp = o0;
            *(ushort4*)(dstp + 4) = o1;
        }
    }
}

extern "C" void kernel_launch(void* const* d_in, const int* in_sizes, int n_in,
                              void* d_out, int out_size, void* d_ws, size_t ws_size,
                              hipStream_t stream) {
    const float* x   = (const float*)d_in[0];
    const int*   ei  = (const int*)d_in[1];
    const int*   src = ei;
    const int*   dst = ei + EE;
    const float* w0a = (const float*)d_in[2];
    const float* b0a = (const float*)d_in[3];
    const float* w0b = (const float*)d_in[4];
    const float* b0b = (const float*)d_in[5];
    const float* w1a = (const float*)d_in[6];
    const float* b1a = (const float*)d_in[7];
    const float* w1b = (const float*)d_in[8];
    const float* b1b = (const float*)d_in[9];
    const float* w2a = (const float*)d_in[10];
    const float* b2a = (const float*)d_in[11];
    const float* w2b = (const float*)d_in[12];
    const float* b2b = (const float*)d_in[13];
    const float* lw  = (const float*)d_in[14];
    const float* lb  = (const float*)d_in[15];
    float* outp = (float*)d_out;

    // workspace layout (2 activation buffers ping-pong)
    ushort* xb  = (ushort*)d_ws;                      // N*CC bf16
    ushort* hbA = xb + (size_t)NN * CC;               // N*CC bf16
    ushort* wT  = hbA + (size_t)NN * CC;              // 6 * 128*128 bf16
    int* col    = (int*)(wT + 6 * CC * CC);           // EE
    int* rowptr    = col + EE;                        // NN+1
    int* cursor    = rowptr + NN + 1;                 // NN
    int* deg       = cursor + NN;                     // NN
    int* blockSums = deg + NN;                        // NB_SCAN
    int* blockOff  = blockSums + NB_SCAN;             // NB_SCAN

    ushort* w0aT = wT;
    ushort* w0bT = wT + 1 * CC * CC;
    ushort* w1aT = wT + 2 * CC * CC;
    ushort* w1bT = wT + 3 * CC * CC;
    ushort* w2aT = wT + 4 * CC * CC;
    ushort* w2bT = wT + 5 * CC * CC;

    const int layerBlocks = (NN / 16 + 3) / 4;        // 1563 (4 waves x 16 rows)
    const int cvtXBlocks  = (NN * CC / 4) / 256;

    // ---- conversions ----
    convert_x_kernel<<<cvtXBlocks, 256, 0, stream>>>(x, xb);
    convert_w6_kernel<<<6 * 64, 256, 0, stream>>>(w0a, w0b, w1a, w1b, w2a, w2b, wT);

    // ---- CSR build ----
    hipMemsetAsync(deg, 0, NN * sizeof(int), stream);
    hist_part<<<NCHUNKS * NRANGE, 256, 0, stream>>>(dst, deg);
    deg_block_reduce<<<NB_SCAN, 256, 0, stream>>>(deg, blockSums);
    scan_offsets<<<1, 64, 0, stream>>>(blockSums, blockOff, rowptr);
    deg_scan_write<<<NB_SCAN, 256, 0, stream>>>(deg, blockOff, rowptr, cursor);
    fill_csr_part<<<NCHUNKS * NRANGE, 256, 0, stream>>>(src, dst, cursor, col);

    // ---- 3 fused layers (head fused into layer 3) ----
    gin_wave<false><<<layerBlocks, 256, 0, stream>>>(xb, rowptr, col,
        w0aT, b0a, w0bT, b0b, hbA, nullptr, nullptr, nullptr);
    gin_wave<false><<<layerBlocks, 256, 0, stream>>>(hbA, rowptr, col,
        w1aT, b1a, w1bT, b1b, xb, nullptr, nullptr, nullptr);
    gin_wave<true><<<layerBlocks, 256, 0, stream>>>(xb, rowptr, col,
        w2aT, b2a, w2bT, b2b, nullptr, lw, lb, outp);
}

// Round 12
// 632.118 us; speedup vs baseline: 1.0743x; 1.0743x over previous
//
#include <hip/hip_runtime.h>
#include <hip/hip_bf16.h>
#include <math.h>

#define NN 100000
#define CC 128
#define EE 1600000
#define SCAN_CHUNK 2048
#define NB_SCAN ((NN + SCAN_CHUNK - 1) / SCAN_CHUNK)  // 49
#define NRANGE 8
#define RNODES (NN / NRANGE)     // 12500
#define EPT 8                    // edges per thread in partitioned edge kernels
#define FCHUNK (256 * EPT)       // 2048 edges per block
#define NCHUNKS ((EE + FCHUNK - 1) / FCHUNK)  // 782

typedef short  bf16x8 __attribute__((ext_vector_type(8)));
typedef float  f32x4  __attribute__((ext_vector_type(4)));
typedef float  f32x4v __attribute__((ext_vector_type(4)));
typedef unsigned short u16x8 __attribute__((ext_vector_type(8)));

#define TPAD 132   // float stride for per-wave T tiles (528 B, 16B-aligned)

__device__ __forceinline__ ushort f2bf(float f) {
    __hip_bfloat16 h = __float2bfloat16(f);   // RNE
    return __builtin_bit_cast(ushort, h);
}
__device__ __forceinline__ float bf2f(ushort u) {
    return __builtin_bit_cast(float, ((unsigned int)u) << 16);
}

// ===========================================================================
// CSR build — R7's exact measured-best forms (EPT=8, plain loads,
// conditional scalar src). fill is atomic-chain-bound at ~20G chains/s.
// ===========================================================================
__global__ void __launch_bounds__(256) hist_part(
    const int* __restrict__ dst, int* __restrict__ deg)
{
    int range = blockIdx.x & (NRANGE - 1);
    int chunk = blockIdx.x >> 3;
    int lo = range * RNODES, hi = lo + RNODES;
    int base = chunk * FCHUNK + threadIdx.x * EPT;
    if (base + EPT <= EE) {
        int4 d0 = *(const int4*)&dst[base];
        int4 d1 = *(const int4*)&dst[base + 4];
        int dd[8] = {d0.x, d0.y, d0.z, d0.w, d1.x, d1.y, d1.z, d1.w};
#pragma unroll
        for (int i = 0; i < 8; ++i) {
            int d = dd[i];
            if (d >= lo && d < hi) atomicAdd(&deg[d], 1);
        }
    } else {
        for (int i = 0; i < EPT; ++i) {
            int e = base + i;
            if (e < EE) {
                int d = dst[e];
                if (d >= lo && d < hi) atomicAdd(&deg[d], 1);
            }
        }
    }
}

__global__ void __launch_bounds__(256) deg_block_reduce(
    const int* __restrict__ deg, int* __restrict__ blockSums)
{
    int base = blockIdx.x * SCAN_CHUNK + threadIdx.x * 8;
    int s = 0;
#pragma unroll
    for (int i = 0; i < 8; ++i) {
        int idx = base + i;
        if (idx < NN) s += deg[idx];
    }
#pragma unroll
    for (int off = 32; off > 0; off >>= 1) s += __shfl_down(s, off);
    __shared__ int ws[4];
    int lane = threadIdx.x & 63, wid = threadIdx.x >> 6;
    if (lane == 0) ws[wid] = s;
    __syncthreads();
    if (threadIdx.x == 0) blockSums[blockIdx.x] = ws[0] + ws[1] + ws[2] + ws[3];
}

__global__ void scan_offsets(const int* __restrict__ blockSums,
                             int* __restrict__ blockOff, int* __restrict__ rowptr)
{
    int lane = threadIdx.x;  // 64 threads
    int v = (lane < NB_SCAN) ? blockSums[lane] : 0;
    int inc = v;
#pragma unroll
    for (int off = 1; off < 64; off <<= 1) {
        int n = __shfl_up(inc, off);
        if (lane >= off) inc += n;
    }
    if (lane < NB_SCAN) blockOff[lane] = inc - v;
    if (lane == 63) rowptr[NN] = EE;
}

__global__ void __launch_bounds__(256) deg_scan_write(
    const int* __restrict__ deg, const int* __restrict__ blockOff,
    int* __restrict__ rowptr, int* __restrict__ cursor)
{
    __shared__ int warpSums[4];
    int base = blockIdx.x * SCAN_CHUNK + threadIdx.x * 8;
    int v[8];
    int s = 0;
#pragma unroll
    for (int i = 0; i < 8; ++i) {
        int idx = base + i;
        v[i] = (idx < NN) ? deg[idx] : 0;
        s += v[i];
    }
    int lane = threadIdx.x & 63, wid = threadIdx.x >> 6;
    int inc = s;
#pragma unroll
    for (int off = 1; off < 64; off <<= 1) {
        int n = __shfl_up(inc, off);
        if (lane >= off) inc += n;
    }
    if (lane == 63) warpSums[wid] = inc;
    __syncthreads();
    int wofs = 0;
#pragma unroll
    for (int w = 0; w < 4; ++w)
        if (w < wid) wofs += warpSums[w];
    int exc = blockOff[blockIdx.x] + wofs + (inc - s);
#pragma unroll
    for (int i = 0; i < 8; ++i) {
        int idx = base + i;
        if (idx < NN) { rowptr[idx] = exc; cursor[idx] = exc; }
        exc += v[i];
    }
}

__global__ void __launch_bounds__(256) fill_csr_part(
    const int* __restrict__ src, const int* __restrict__ dst,
    int* __restrict__ cursor, int* __restrict__ col)
{
    int range = blockIdx.x & (NRANGE - 1);
    int chunk = blockIdx.x >> 3;
    int lo = range * RNODES, hi = lo + RNODES;
    int base = chunk * FCHUNK + threadIdx.x * EPT;
    if (base + EPT <= EE) {
        int4 d0 = *(const int4*)&dst[base];
        int4 d1 = *(const int4*)&dst[base + 4];
        int dd[8] = {d0.x, d0.y, d0.z, d0.w, d1.x, d1.y, d1.z, d1.w};
#pragma unroll
        for (int i = 0; i < 8; ++i) {
            int d = dd[i];
            if (d >= lo && d < hi) {
                int s = src[base + i];
                int pos = atomicAdd(&cursor[d], 1);
                col[pos] = s;
            }
        }
    } else {
        for (int i = 0; i < EPT; ++i) {
            int e = base + i;
            if (e < EE) {
                int d = dst[e];
                if (d >= lo && d < hi) {
                    int s = src[e];
                    int pos = atomicAdd(&cursor[d], 1);
                    col[pos] = s;
                }
            }
        }
    }
}

// ===========================================================================
// Conversions
// ===========================================================================
__global__ void __launch_bounds__(256) convert_x_kernel(
    const float* __restrict__ x, ushort* __restrict__ xb)
{
    int i = blockIdx.x * 256 + threadIdx.x;   // float4 groups; NN*CC/4 total
    f32x4v v = __builtin_nontemporal_load((const f32x4v*)x + i);  // single-use stream
    ushort4 o;
    o.x = f2bf(v[0]); o.y = f2bf(v[1]); o.z = f2bf(v[2]); o.w = f2bf(v[3]);
    ((ushort4*)xb)[i] = o;
}

__global__ void __launch_bounds__(256) convert_w6_kernel(
    const float* __restrict__ w0, const float* __restrict__ w1,
    const float* __restrict__ w2, const float* __restrict__ w3,
    const float* __restrict__ w4, const float* __restrict__ w5,
    ushort* __restrict__ wt)
{
    int i = blockIdx.x * 256 + threadIdx.x;  // 6*16384
    int mat = i >> 14;
    int rem = i & 16383;
    int k = rem >> 7, n = rem & 127;
    const float* w = (mat == 0) ? w0 : (mat == 1) ? w1 : (mat == 2) ? w2
                   : (mat == 3) ? w3 : (mat == 4) ? w4 : w5;
    wt[mat * 16384 + n * 128 + k] = f2bf(w[k * 128 + n]);
}

// ===========================================================================
// Standalone max-occupancy gather: agg[n] = h[n] + sum_nbr h[nbr]  (bf16)
// 6250 blocks, ~73% occupancy — at the random-graph L2-miss floor.
// ===========================================================================
__global__ void __launch_bounds__(256) gather_agg(
    const ushort* __restrict__ hin, const int* __restrict__ rowptr,
    const int* __restrict__ col, ushort* __restrict__ agg)
{
    const int grp    = threadIdx.x >> 4;            // 0..15
    const int lane16 = threadIdx.x & 15;
    const int gbase  = (threadIdx.x & 63) & 48;     // group base lane in wave
    const int n = blockIdx.x * 16 + grp;            // 6250*16 = 100000 exact
    const u16x8* hp = (const u16x8*)hin;

    u16x8 self = hp[n * 16 + lane16];
    float s0[8], s1[8], s2[8], s3[8];
#pragma unroll
    for (int k = 0; k < 8; ++k) {
        s0[k] = bf2f(self[k]); s1[k] = 0.f; s2[k] = 0.f; s3[k] = 0.f;
    }

    int beg = rowptr[n], end = rowptr[n + 1];
    while (beg < end) {
        int take = end - beg;
        if (take > 16) take = 16;
        int ci = (lane16 < take) ? col[beg + lane16] : 0;
        int j = 0;
        for (; j + 4 <= take; j += 4) {
            int n0 = __shfl(ci, gbase + j + 0);
            int n1 = __shfl(ci, gbase + j + 1);
            int n2 = __shfl(ci, gbase + j + 2);
            int n3 = __shfl(ci, gbase + j + 3);
            u16x8 a0 = hp[n0 * 16 + lane16];
            u16x8 a1 = hp[n1 * 16 + lane16];
            u16x8 a2 = hp[n2 * 16 + lane16];
            u16x8 a3 = hp[n3 * 16 + lane16];
#pragma unroll
            for (int k = 0; k < 8; ++k) {
                s0[k] += bf2f(a0[k]); s1[k] += bf2f(a1[k]);
                s2[k] += bf2f(a2[k]); s3[k] += bf2f(a3[k]);
            }
        }
        for (; j < take; ++j) {
            int n0 = __shfl(ci, gbase + j);
            u16x8 a0 = hp[n0 * 16 + lane16];
#pragma unroll
            for (int k = 0; k < 8; ++k) s0[k] += bf2f(a0[k]);
        }
        beg += take;
    }

    bf16x8 o;
#pragma unroll
    for (int k = 0; k < 8; ++k) o[k] = (short)f2bf(s0[k] + s1[k] + s2[k] + s3[k]);
    *(bf16x8*)&((ushort*)agg)[n * CC + lane16 * 8] = o;
}

// ===========================================================================
// Single-wave barrier-free MFMA MLP: 64 threads/block, 16 rows/wave.
// 6250 blocks (24/CU queued), LDS 8.4 KB/block -> high residency; waves in
// different phases cover each other's weight-load / A-load latency.
// ===========================================================================
template <bool FUSE_HEAD>
__global__ void __launch_bounds__(64) mlp_wave1(
    const ushort* __restrict__ hin,
    const ushort* __restrict__ waT, const float* __restrict__ ba,
    const ushort* __restrict__ wbT, const float* __restrict__ bb,
    ushort* __restrict__ hout,
    const float* __restrict__ lw, const float* __restrict__ lb,
    float* __restrict__ out)
{
    __shared__ float T[16 * TPAD];   // 8448 B, per-wave private

    const int lane = threadIdx.x;
    const int quad = lane >> 4;
    const int l16  = lane & 15;
    const int wrow0 = blockIdx.x * 16;     // 6250 * 16 = 100000 exact

    // ---- stage-1 A fragments straight from global ----
    bf16x8 afrag[4];
#pragma unroll
    for (int kk = 0; kk < 4; ++kk)
        afrag[kk] = *(const bf16x8*)&hin[(wrow0 + l16) * CC + kk * 32 + quad * 8];

    // ---- stage 1: T = relu(A @ Wa + ba) ----
    f32x4 acc[8];
#pragma unroll
    for (int nt = 0; nt < 8; ++nt) acc[nt] = (f32x4){0.f, 0.f, 0.f, 0.f};
#pragma unroll
    for (int kk = 0; kk < 4; ++kk) {
#pragma unroll
        for (int nt = 0; nt < 8; ++nt) {
            bf16x8 bfrag = *(const bf16x8*)&waT[(nt * 16 + l16) * CC + kk * 32 + quad * 8];
            acc[nt] = __builtin_amdgcn_mfma_f32_16x16x32_bf16(afrag[kk], bfrag, acc[nt], 0, 0, 0);
        }
    }
#pragma unroll
    for (int nt = 0; nt < 8; ++nt) {
        int colc = nt * 16 + l16;
        float bias = ba[colc];
#pragma unroll
        for (int r = 0; r < 4; ++r) {
            float v = acc[nt][r] + bias;
            T[(quad * 4 + r) * TPAD + colc] = fmaxf(v, 0.f);
        }
    }
    // within-wave LDS write->read ordering: compiler lgkmcnt, no barrier

    // ---- stage-2 A fragments from T (cvt fp32 -> bf16) ----
    bf16x8 a2[4];
#pragma unroll
    for (int kk = 0; kk < 4; ++kk) {
        const float* tp = &T[l16 * TPAD + kk * 32 + quad * 8];
        float4 t0 = *(const float4*)tp;
        float4 t1 = *(const float4*)(tp + 4);
        bf16x8 f;
        f[0] = (short)f2bf(t0.x); f[1] = (short)f2bf(t0.y);
        f[2] = (short)f2bf(t0.z); f[3] = (short)f2bf(t0.w);
        f[4] = (short)f2bf(t1.x); f[5] = (short)f2bf(t1.y);
        f[6] = (short)f2bf(t1.z); f[7] = (short)f2bf(t1.w);
        a2[kk] = f;
    }

    // ---- stage 2: out = elu(T @ Wb + bb) ----
    f32x4 acc2[8];
#pragma unroll
    for (int nt = 0; nt < 8; ++nt) acc2[nt] = (f32x4){0.f, 0.f, 0.f, 0.f};
#pragma unroll
    for (int kk = 0; kk < 4; ++kk) {
#pragma unroll
        for (int nt = 0; nt < 8; ++nt) {
            bf16x8 bfrag = *(const bf16x8*)&wbT[(nt * 16 + l16) * CC + kk * 32 + quad * 8];
            acc2[nt] = __builtin_amdgcn_mfma_f32_16x16x32_bf16(a2[kk], bfrag, acc2[nt], 0, 0, 0);
        }
    }

    if (FUSE_HEAD) {
        float part[4] = {0.f, 0.f, 0.f, 0.f};
#pragma unroll
        for (int nt = 0; nt < 8; ++nt) {
            int colc = nt * 16 + l16;
            float bias = bb[colc];
            float w = lw[colc];
#pragma unroll
            for (int r = 0; r < 4; ++r) {
                float v = acc2[nt][r] + bias;
                v = v > 0.f ? v : expm1f(v);
                part[r] += v * w;
            }
        }
#pragma unroll
        for (int r = 0; r < 4; ++r) {
#pragma unroll
            for (int off = 8; off > 0; off >>= 1)
                part[r] += __shfl_xor(part[r], off);
        }
        if (l16 == 0) {
            float lbv = lb[0];
#pragma unroll
            for (int r = 0; r < 4; ++r) {
                int grow = wrow0 + quad * 4 + r;
                float z = part[r] + lbv;
                out[grow] = 1.f / (1.f + expf(-z));
            }
        }
    } else {
        // elu -> T (safe: same-wave a2 reads already returned) -> bf16 store
#pragma unroll
        for (int nt = 0; nt < 8; ++nt) {
            int colc = nt * 16 + l16;
            float bias = bb[colc];
#pragma unroll
            for (int r = 0; r < 4; ++r) {
                float v = acc2[nt][r] + bias;
                T[(quad * 4 + r) * TPAD + colc] = v > 0.f ? v : expm1f(v);
            }
        }
#pragma unroll
        for (int i = 0; i < 4; ++i) {
            int r  = i * 4 + quad;           // 0..15
            int cv = l16;                    // 16B chunk (8 values)
            const float* tp = &T[r * TPAD + cv * 8];
            float4 t0 = *(const float4*)tp;
            float4 t1 = *(const float4*)(tp + 4);
            ushort4 o0, o1;
            o0.x = f2bf(t0.x); o0.y = f2bf(t0.y); o0.z = f2bf(t0.z); o0.w = f2bf(t0.w);
            o1.x = f2bf(t1.x); o1.y = f2bf(t1.y); o1.z = f2bf(t1.z); o1.w = f2bf(t1.w);
            ushort* dstp = &hout[(wrow0 + r) * CC + cv * 8];
            *(ushort4*)dstp = o0;
            *(ushort4*)(dstp + 4) = o1;
        }
    }
}

extern "C" void kernel_launch(void* const* d_in, const int* in_sizes, int n_in,
                              void* d_out, int out_size, void* d_ws, size_t ws_size,
                              hipStream_t stream) {
    const float* x   = (const float*)d_in[0];
    const int*   ei  = (const int*)d_in[1];
    const int*   src = ei;
    const int*   dst = ei + EE;
    const float* w0a = (const float*)d_in[2];
    const float* b0a = (const float*)d_in[3];
    const float* w0b = (const float*)d_in[4];
    const float* b0b = (const float*)d_in[5];
    const float* w1a = (const float*)d_in[6];
    const float* b1a = (const float*)d_in[7];
    const float* w1b = (const float*)d_in[8];
    const float* b1b = (const float*)d_in[9];
    const float* w2a = (const float*)d_in[10];
    const float* b2a = (const float*)d_in[11];
    const float* w2b = (const float*)d_in[12];
    const float* b2b = (const float*)d_in[13];
    const float* lw  = (const float*)d_in[14];
    const float* lb  = (const float*)d_in[15];
    float* outp = (float*)d_out;

    // workspace layout (xb reused as layer-2 output)
    ushort* xb  = (ushort*)d_ws;                      // N*CC bf16
    ushort* hbA = xb + (size_t)NN * CC;               // N*CC bf16
    ushort* agg = hbA + (size_t)NN * CC;              // N*CC bf16
    ushort* wT  = agg + (size_t)NN * CC;              // 6 * 128*128 bf16
    int* col    = (int*)(wT + 6 * CC * CC);           // EE
    int* rowptr    = col + EE;                        // NN+1
    int* cursor    = rowptr + NN + 1;                 // NN
    int* deg       = cursor + NN;                     // NN
    int* blockSums = deg + NN;                        // NB_SCAN
    int* blockOff  = blockSums + NB_SCAN;             // NB_SCAN

    ushort* w0aT = wT;
    ushort* w0bT = wT + 1 * CC * CC;
    ushort* w1aT = wT + 2 * CC * CC;
    ushort* w1bT = wT + 3 * CC * CC;
    ushort* w2aT = wT + 4 * CC * CC;
    ushort* w2bT = wT + 5 * CC * CC;

    const int gatherBlocks = NN / 16;                 // 6250
    const int mlpBlocks    = NN / 16;                 // 6250 (1 wave x 16 rows)
    const int cvtXBlocks   = (NN * CC / 4) / 256;

    // ---- conversions ----
    convert_x_kernel<<<cvtXBlocks, 256, 0, stream>>>(x, xb);
    convert_w6_kernel<<<6 * 64, 256, 0, stream>>>(w0a, w0b, w1a, w1b, w2a, w2b, wT);

    // ---- CSR build ----
    hipMemsetAsync(deg, 0, NN * sizeof(int), stream);
    hist_part<<<NCHUNKS * NRANGE, 256, 0, stream>>>(dst, deg);
    deg_block_reduce<<<NB_SCAN, 256, 0, stream>>>(deg, blockSums);
    scan_offsets<<<1, 64, 0, stream>>>(blockSums, blockOff, rowptr);
    deg_scan_write<<<NB_SCAN, 256, 0, stream>>>(deg, blockOff, rowptr, cursor);
    fill_csr_part<<<NCHUNKS * NRANGE, 256, 0, stream>>>(src, dst, cursor, col);

    // ---- layer 1 ----
    gather_agg<<<gatherBlocks, 256, 0, stream>>>(xb, rowptr, col, agg);
    mlp_wave1<false><<<mlpBlocks, 64, 0, stream>>>(agg, w0aT, b0a, w0bT, b0b, hbA,
                                                   nullptr, nullptr, nullptr);
    // ---- layer 2 (output into xb) ----
    gather_agg<<<gatherBlocks, 256, 0, stream>>>(hbA, rowptr, col, agg);
    mlp_wave1<false><<<mlpBlocks, 64, 0, stream>>>(agg, w1aT, b1a, w1bT, b1b, xb,
                                                   nullptr, nullptr, nullptr);
    // ---- layer 3 + fused head ----
    gather_agg<<<gatherBlocks, 256, 0, stream>>>(xb, rowptr, col, agg);
    mlp_wave1<true><<<mlpBlocks, 64, 0, stream>>>(agg, w2aT, b2a, w2bT, b2b, nullptr,
                                                  lw, lb, outp);
}

// Round 13
// 546.060 us; speedup vs baseline: 1.2436x; 1.1576x over previous
//
#include <hip/hip_runtime.h>
#include <hip/hip_bf16.h>
#include <math.h>

#define NN 100000
#define CC 128
#define EE 1600000
#define SCAN_CHUNK 2048
#define NB_SCAN ((NN + SCAN_CHUNK - 1) / SCAN_CHUNK)  // 49
#define NRANGE 8
#define RNODES (NN / NRANGE)     // 12500
#define EPT 8                    // edges per thread in partitioned edge kernels
#define FCHUNK (256 * EPT)       // 2048 edges per block
#define NCHUNKS ((EE + FCHUNK - 1) / FCHUNK)  // 782

typedef short  bf16x8 __attribute__((ext_vector_type(8)));
typedef float  f32x4  __attribute__((ext_vector_type(4)));
typedef float  f32x4v __attribute__((ext_vector_type(4)));
typedef unsigned short u16x8 __attribute__((ext_vector_type(8)));

#define WPAD 136   // ushort stride for LDS weight rows (272 B -> 2-way bank alias, free)
#define TPAD 132   // float stride for per-wave T tiles (528 B)
#define MLPB 256   // persistent MLP blocks (1 per CU)

__device__ __forceinline__ ushort f2bf(float f) {
    __hip_bfloat16 h = __float2bfloat16(f);   // RNE
    return __builtin_bit_cast(ushort, h);
}
__device__ __forceinline__ float bf2f(ushort u) {
    return __builtin_bit_cast(float, ((unsigned int)u) << 16);
}

// ===========================================================================
// CSR build — R7/R12 exact measured-best forms (fill ~71 us, atomic-chain
// bound at ~20G chains/s; EPT=8, plain loads, conditional scalar src).
// ===========================================================================
__global__ void __launch_bounds__(256) hist_part(
    const int* __restrict__ dst, int* __restrict__ deg)
{
    int range = blockIdx.x & (NRANGE - 1);
    int chunk = blockIdx.x >> 3;
    int lo = range * RNODES, hi = lo + RNODES;
    int base = chunk * FCHUNK + threadIdx.x * EPT;
    if (base + EPT <= EE) {
        int4 d0 = *(const int4*)&dst[base];
        int4 d1 = *(const int4*)&dst[base + 4];
        int dd[8] = {d0.x, d0.y, d0.z, d0.w, d1.x, d1.y, d1.z, d1.w};
#pragma unroll
        for (int i = 0; i < 8; ++i) {
            int d = dd[i];
            if (d >= lo && d < hi) atomicAdd(&deg[d], 1);
        }
    } else {
        for (int i = 0; i < EPT; ++i) {
            int e = base + i;
            if (e < EE) {
                int d = dst[e];
                if (d >= lo && d < hi) atomicAdd(&deg[d], 1);
            }
        }
    }
}

__global__ void __launch_bounds__(256) deg_block_reduce(
    const int* __restrict__ deg, int* __restrict__ blockSums)
{
    int base = blockIdx.x * SCAN_CHUNK + threadIdx.x * 8;
    int s = 0;
#pragma unroll
    for (int i = 0; i < 8; ++i) {
        int idx = base + i;
        if (idx < NN) s += deg[idx];
    }
#pragma unroll
    for (int off = 32; off > 0; off >>= 1) s += __shfl_down(s, off);
    __shared__ int ws[4];
    int lane = threadIdx.x & 63, wid = threadIdx.x >> 6;
    if (lane == 0) ws[wid] = s;
    __syncthreads();
    if (threadIdx.x == 0) blockSums[blockIdx.x] = ws[0] + ws[1] + ws[2] + ws[3];
}

__global__ void scan_offsets(const int* __restrict__ blockSums,
                             int* __restrict__ blockOff, int* __restrict__ rowptr)
{
    int lane = threadIdx.x;  // 64 threads
    int v = (lane < NB_SCAN) ? blockSums[lane] : 0;
    int inc = v;
#pragma unroll
    for (int off = 1; off < 64; off <<= 1) {
        int n = __shfl_up(inc, off);
        if (lane >= off) inc += n;
    }
    if (lane < NB_SCAN) blockOff[lane] = inc - v;
    if (lane == 63) rowptr[NN] = EE;
}

__global__ void __launch_bounds__(256) deg_scan_write(
    const int* __restrict__ deg, const int* __restrict__ blockOff,
    int* __restrict__ rowptr, int* __restrict__ cursor)
{
    __shared__ int warpSums[4];
    int base = blockIdx.x * SCAN_CHUNK + threadIdx.x * 8;
    int v[8];
    int s = 0;
#pragma unroll
    for (int i = 0; i < 8; ++i) {
        int idx = base + i;
        v[i] = (idx < NN) ? deg[idx] : 0;
        s += v[i];
    }
    int lane = threadIdx.x & 63, wid = threadIdx.x >> 6;
    int inc = s;
#pragma unroll
    for (int off = 1; off < 64; off <<= 1) {
        int n = __shfl_up(inc, off);
        if (lane >= off) inc += n;
    }
    if (lane == 63) warpSums[wid] = inc;
    __syncthreads();
    int wofs = 0;
#pragma unroll
    for (int w = 0; w < 4; ++w)
        if (w < wid) wofs += warpSums[w];
    int exc = blockOff[blockIdx.x] + wofs + (inc - s);
#pragma unroll
    for (int i = 0; i < 8; ++i) {
        int idx = base + i;
        if (idx < NN) { rowptr[idx] = exc; cursor[idx] = exc; }
        exc += v[i];
    }
}

__global__ void __launch_bounds__(256) fill_csr_part(
    const int* __restrict__ src, const int* __restrict__ dst,
    int* __restrict__ cursor, int* __restrict__ col)
{
    int range = blockIdx.x & (NRANGE - 1);
    int chunk = blockIdx.x >> 3;
    int lo = range * RNODES, hi = lo + RNODES;
    int base = chunk * FCHUNK + threadIdx.x * EPT;
    if (base + EPT <= EE) {
        int4 d0 = *(const int4*)&dst[base];
        int4 d1 = *(const int4*)&dst[base + 4];
        int dd[8] = {d0.x, d0.y, d0.z, d0.w, d1.x, d1.y, d1.z, d1.w};
#pragma unroll
        for (int i = 0; i < 8; ++i) {
            int d = dd[i];
            if (d >= lo && d < hi) {
                int s = src[base + i];
                int pos = atomicAdd(&cursor[d], 1);
                col[pos] = s;
            }
        }
    } else {
        for (int i = 0; i < EPT; ++i) {
            int e = base + i;
            if (e < EE) {
                int d = dst[e];
                if (d >= lo && d < hi) {
                    int s = src[e];
                    int pos = atomicAdd(&cursor[d], 1);
                    col[pos] = s;
                }
            }
        }
    }
}

// ===========================================================================
// Conversions (convert_x also zeroes deg -> one fewer dispatch)
// ===========================================================================
__global__ void __launch_bounds__(256) convert_x_kernel(
    const float* __restrict__ x, ushort* __restrict__ xb, int* __restrict__ deg)
{
    int i = blockIdx.x * 256 + threadIdx.x;   // float4 groups; NN*CC/4 total
    f32x4v v = __builtin_nontemporal_load((const f32x4v*)x + i);  // single-use stream
    ushort4 o;
    o.x = f2bf(v[0]); o.y = f2bf(v[1]); o.z = f2bf(v[2]); o.w = f2bf(v[3]);
    ((ushort4*)xb)[i] = o;
    if (i < NN) deg[i] = 0;
}

__global__ void __launch_bounds__(256) convert_w6_kernel(
    const float* __restrict__ w0, const float* __restrict__ w1,
    const float* __restrict__ w2, const float* __restrict__ w3,
    const float* __restrict__ w4, const float* __restrict__ w5,
    ushort* __restrict__ wt)
{
    int i = blockIdx.x * 256 + threadIdx.x;  // 6*16384
    int mat = i >> 14;
    int rem = i & 16383;
    int k = rem >> 7, n = rem & 127;
    const float* w = (mat == 0) ? w0 : (mat == 1) ? w1 : (mat == 2) ? w2
                   : (mat == 3) ? w3 : (mat == 4) ? w4 : w5;
    wt[mat * 16384 + n * 128 + k] = f2bf(w[k * 128 + n]);
}

// ===========================================================================
// Standalone max-occupancy gather: agg[n] = h[n] + sum_nbr h[nbr]  (bf16)
// At the random-graph L2-miss floor (~67 us/layer).
// ===========================================================================
__global__ void __launch_bounds__(256) gather_agg(
    const ushort* __restrict__ hin, const int* __restrict__ rowptr,
    const int* __restrict__ col, ushort* __restrict__ agg)
{
    const int grp    = threadIdx.x >> 4;            // 0..15
    const int lane16 = threadIdx.x & 15;
    const int gbase  = (threadIdx.x & 63) & 48;     // group base lane in wave
    const int n = blockIdx.x * 16 + grp;            // 6250*16 = 100000 exact
    const u16x8* hp = (const u16x8*)hin;

    u16x8 self = hp[n * 16 + lane16];
    float s0[8], s1[8], s2[8], s3[8];
#pragma unroll
    for (int k = 0; k < 8; ++k) {
        s0[k] = bf2f(self[k]); s1[k] = 0.f; s2[k] = 0.f; s3[k] = 0.f;
    }

    int beg = rowptr[n], end = rowptr[n + 1];
    while (beg < end) {
        int take = end - beg;
        if (take > 16) take = 16;
        int ci = (lane16 < take) ? col[beg + lane16] : 0;
        int j = 0;
        for (; j + 4 <= take; j += 4) {
            int n0 = __shfl(ci, gbase + j + 0);
            int n1 = __shfl(ci, gbase + j + 1);
            int n2 = __shfl(ci, gbase + j + 2);
            int n3 = __shfl(ci, gbase + j + 3);
            u16x8 a0 = hp[n0 * 16 + lane16];
            u16x8 a1 = hp[n1 * 16 + lane16];
            u16x8 a2 = hp[n2 * 16 + lane16];
            u16x8 a3 = hp[n3 * 16 + lane16];
#pragma unroll
            for (int k = 0; k < 8; ++k) {
                s0[k] += bf2f(a0[k]); s1[k] += bf2f(a1[k]);
                s2[k] += bf2f(a2[k]); s3[k] += bf2f(a3[k]);
            }
        }
        for (; j < take; ++j) {
            int n0 = __shfl(ci, gbase + j);
            u16x8 a0 = hp[n0 * 16 + lane16];
#pragma unroll
            for (int k = 0; k < 8; ++k) s0[k] += bf2f(a0[k]);
        }
        beg += take;
    }

    bf16x8 o;
#pragma unroll
    for (int k = 0; k < 8; ++k) o[k] = (short)f2bf(s0[k] + s1[k] + s2[k] + s3[k]);
    *(bf16x8*)&((ushort*)agg)[n * CC + lane16 * 8] = o;
}

// ===========================================================================
// Persistent weights-in-LDS MFMA MLP: 256 blocks (1/CU), 4 waves/block.
// Block stages Wa+Wb into LDS once (padded rows, 2-way bank alias = free),
// one barrier, then waves grid-stride over 16-row tiles barrier-free with
// next-tile A prefetch. B-frags: ds_read_b128 (~12cyc) instead of L2 loads.
// LDS: 2*34816 (weights) + 33792 (T) = 103424 B.
// ===========================================================================
template <bool FUSE_HEAD>
__global__ void __launch_bounds__(256) mlp_persist(
    const ushort* __restrict__ hin,
    const ushort* __restrict__ waT, const float* __restrict__ ba,
    const ushort* __restrict__ wbT, const float* __restrict__ bb,
    ushort* __restrict__ hout,
    const float* __restrict__ lw, const float* __restrict__ lb,
    float* __restrict__ out)
{
    __shared__ ushort WaS[CC * WPAD];      // [n][k], row stride 136
    __shared__ ushort WbS[CC * WPAD];
    __shared__ float  Tt[4][16 * TPAD];    // per-wave private T

    const int tid = threadIdx.x;

    // ---- cooperative weight staging (coalesced 16B chunks) ----
    for (int i = tid; i < CC * 16; i += 256) {         // 2048 chunks per matrix
        int row = i >> 4, ch = i & 15;
        *(bf16x8*)&WaS[row * WPAD + ch * 8] = *(const bf16x8*)&waT[row * CC + ch * 8];
        *(bf16x8*)&WbS[row * WPAD + ch * 8] = *(const bf16x8*)&wbT[row * CC + ch * 8];
    }
    __syncthreads();

    const int wave = tid >> 6;
    const int lane = tid & 63;
    const int quad = lane >> 4;
    const int l16  = lane & 15;
    float* T = Tt[wave];
    const int nTiles = NN / 16;            // 6250
    const int stride = MLPB * 4;           // 1024

    int wv = blockIdx.x * 4 + wave;
    if (wv >= nTiles) return;

    // prefetch first tile's A fragments
    bf16x8 af[4];
#pragma unroll
    for (int kk = 0; kk < 4; ++kk)
        af[kk] = *(const bf16x8*)&hin[(wv * 16 + l16) * CC + kk * 32 + quad * 8];

    while (true) {
        const int wrow0 = wv * 16;
        const int wnext = wv + stride;

        // prefetch next tile's A fragments (independent of current compute)
        bf16x8 afn[4];
        if (wnext < nTiles) {
#pragma unroll
            for (int kk = 0; kk < 4; ++kk)
                afn[kk] = *(const bf16x8*)&hin[(wnext * 16 + l16) * CC + kk * 32 + quad * 8];
        }

        // ---- stage 1: T = relu(A @ Wa + ba), B from LDS ----
        f32x4 acc[8];
#pragma unroll
        for (int nt = 0; nt < 8; ++nt) acc[nt] = (f32x4){0.f, 0.f, 0.f, 0.f};
#pragma unroll
        for (int kk = 0; kk < 4; ++kk) {
#pragma unroll
            for (int nt = 0; nt < 8; ++nt) {
                bf16x8 bfrag = *(const bf16x8*)&WaS[(nt * 16 + l16) * WPAD + kk * 32 + quad * 8];
                acc[nt] = __builtin_amdgcn_mfma_f32_16x16x32_bf16(af[kk], bfrag, acc[nt], 0, 0, 0);
            }
        }
#pragma unroll
        for (int nt = 0; nt < 8; ++nt) {
            int colc = nt * 16 + l16;
            float bias = ba[colc];
#pragma unroll
            for (int r = 0; r < 4; ++r) {
                float v = acc[nt][r] + bias;
                T[(quad * 4 + r) * TPAD + colc] = fmaxf(v, 0.f);
            }
        }
        // within-wave LDS write->read: compiler lgkmcnt, no barrier

        // ---- stage-2 A fragments from T (cvt fp32 -> bf16) ----
        bf16x8 a2[4];
#pragma unroll
        for (int kk = 0; kk < 4; ++kk) {
            const float* tp = &T[l16 * TPAD + kk * 32 + quad * 8];
            float4 t0 = *(const float4*)tp;
            float4 t1 = *(const float4*)(tp + 4);
            bf16x8 f;
            f[0] = (short)f2bf(t0.x); f[1] = (short)f2bf(t0.y);
            f[2] = (short)f2bf(t0.z); f[3] = (short)f2bf(t0.w);
            f[4] = (short)f2bf(t1.x); f[5] = (short)f2bf(t1.y);
            f[6] = (short)f2bf(t1.z); f[7] = (short)f2bf(t1.w);
            a2[kk] = f;
        }

        // ---- stage 2: out = elu(T @ Wb + bb), B from LDS ----
        f32x4 acc2[8];
#pragma unroll
        for (int nt = 0; nt < 8; ++nt) acc2[nt] = (f32x4){0.f, 0.f, 0.f, 0.f};
#pragma unroll
        for (int kk = 0; kk < 4; ++kk) {
#pragma unroll
            for (int nt = 0; nt < 8; ++nt) {
                bf16x8 bfrag = *(const bf16x8*)&WbS[(nt * 16 + l16) * WPAD + kk * 32 + quad * 8];
                acc2[nt] = __builtin_amdgcn_mfma_f32_16x16x32_bf16(a2[kk], bfrag, acc2[nt], 0, 0, 0);
            }
        }

        if (FUSE_HEAD) {
            float part[4] = {0.f, 0.f, 0.f, 0.f};
#pragma unroll
            for (int nt = 0; nt < 8; ++nt) {
                int colc = nt * 16 + l16;
                float bias = bb[colc];
                float w = lw[colc];
#pragma unroll
                for (int r = 0; r < 4; ++r) {
                    float v = acc2[nt][r] + bias;
                    v = v > 0.f ? v : expm1f(v);
                    part[r] += v * w;
                }
            }
#pragma unroll
            for (int r = 0; r < 4; ++r) {
#pragma unroll
                for (int off = 8; off > 0; off >>= 1)
                    part[r] += __shfl_xor(part[r], off);
            }
            if (l16 == 0) {
                float lbv = lb[0];
#pragma unroll
                for (int r = 0; r < 4; ++r) {
                    int grow = wrow0 + quad * 4 + r;
                    float z = part[r] + lbv;
                    out[grow] = 1.f / (1.f + expf(-z));
                }
            }
        } else {
            // elu -> T (safe: same-wave a2 reads returned) -> coalesced bf16 store
#pragma unroll
            for (int nt = 0; nt < 8; ++nt) {
                int colc = nt * 16 + l16;
                float bias = bb[colc];
#pragma unroll
                for (int r = 0; r < 4; ++r) {
                    float v = acc2[nt][r] + bias;
                    T[(quad * 4 + r) * TPAD + colc] = v > 0.f ? v : expm1f(v);
                }
            }
#pragma unroll
            for (int i = 0; i < 4; ++i) {
                int r  = i * 4 + quad;           // 0..15
                int cv = l16;                    // 16B chunk (8 values)
                const float* tp = &T[r * TPAD + cv * 8];
                float4 t0 = *(const float4*)tp;
                float4 t1 = *(const float4*)(tp + 4);
                ushort4 o0, o1;
                o0.x = f2bf(t0.x); o0.y = f2bf(t0.y); o0.z = f2bf(t0.z); o0.w = f2bf(t0.w);
                o1.x = f2bf(t1.x); o1.y = f2bf(t1.y); o1.z = f2bf(t1.z); o1.w = f2bf(t1.w);
                ushort* dstp = &hout[(wrow0 + r) * CC + cv * 8];
                *(ushort4*)dstp = o0;
                *(ushort4*)(dstp + 4) = o1;
            }
        }

        if (wnext >= nTiles) break;
        wv = wnext;
#pragma unroll
        for (int kk = 0; kk < 4; ++kk) af[kk] = afn[kk];
    }
}

extern "C" void kernel_launch(void* const* d_in, const int* in_sizes, int n_in,
                              void* d_out, int out_size, void* d_ws, size_t ws_size,
                              hipStream_t stream) {
    const float* x   = (const float*)d_in[0];
    const int*   ei  = (const int*)d_in[1];
    const int*   src = ei;
    const int*   dst = ei + EE;
    const float* w0a = (const float*)d_in[2];
    const float* b0a = (const float*)d_in[3];
    const float* w0b = (const float*)d_in[4];
    const float* b0b = (const float*)d_in[5];
    const float* w1a = (const float*)d_in[6];
    const float* b1a = (const float*)d_in[7];
    const float* w1b = (const float*)d_in[8];
    const float* b1b = (const float*)d_in[9];
    const float* w2a = (const float*)d_in[10];
    const float* b2a = (const float*)d_in[11];
    const float* w2b = (const float*)d_in[12];
    const float* b2b = (const float*)d_in[13];
    const float* lw  = (const float*)d_in[14];
    const float* lb  = (const float*)d_in[15];
    float* outp = (float*)d_out;

    // workspace layout (xb reused as layer-2 output)
    ushort* xb  = (ushort*)d_ws;                      // N*CC bf16
    ushort* hbA = xb + (size_t)NN * CC;               // N*CC bf16
    ushort* agg = hbA + (size_t)NN * CC;              // N*CC bf16
    ushort* wT  = agg + (size_t)NN * CC;              // 6 * 128*128 bf16
    int* col    = (int*)(wT + 6 * CC * CC);           // EE
    int* rowptr    = col + EE;                        // NN+1
    int* cursor    = rowptr + NN + 1;                 // NN
    int* deg       = cursor + NN;                     // NN
    int* blockSums = deg + NN;                        // NB_SCAN
    int* blockOff  = blockSums + NB_SCAN;             // NB_SCAN

    ushort* w0aT = wT;
    ushort* w0bT = wT + 1 * CC * CC;
    ushort* w1aT = wT + 2 * CC * CC;
    ushort* w1bT = wT + 3 * CC * CC;
    ushort* w2aT = wT + 4 * CC * CC;
    ushort* w2bT = wT + 5 * CC * CC;

    const int gatherBlocks = NN / 16;                 // 6250
    const int cvtXBlocks   = (NN * CC / 4) / 256;     // 12500

    // ---- conversions (convert_x also zeroes deg) ----
    convert_x_kernel<<<cvtXBlocks, 256, 0, stream>>>(x, xb, deg);
    convert_w6_kernel<<<6 * 64, 256, 0, stream>>>(w0a, w0b, w1a, w1b, w2a, w2b, wT);

    // ---- CSR build ----
    hist_part<<<NCHUNKS * NRANGE, 256, 0, stream>>>(dst, deg);
    deg_block_reduce<<<NB_SCAN, 256, 0, stream>>>(deg, blockSums);
    scan_offsets<<<1, 64, 0, stream>>>(blockSums, blockOff, rowptr);
    deg_scan_write<<<NB_SCAN, 256, 0, stream>>>(deg, blockOff, rowptr, cursor);
    fill_csr_part<<<NCHUNKS * NRANGE, 256, 0, stream>>>(src, dst, cursor, col);

    // ---- layer 1 ----
    gather_agg<<<gatherBlocks, 256, 0, stream>>>(xb, rowptr, col, agg);
    mlp_persist<false><<<MLPB, 256, 0, stream>>>(agg, w0aT, b0a, w0bT, b0b, hbA,
                                                 nullptr, nullptr, nullptr);
    // ---- layer 2 (output into xb) ----
    gather_agg<<<gatherBlocks, 256, 0, stream>>>(hbA, rowptr, col, agg);
    mlp_persist<false><<<MLPB, 256, 0, stream>>>(agg, w1aT, b1a, w1bT, b1b, xb,
                                                 nullptr, nullptr, nullptr);
    // ---- layer 3 + fused head ----
    gather_agg<<<gatherBlocks, 256, 0, stream>>>(xb, rowptr, col, agg);
    mlp_persist<true><<<MLPB, 256, 0, stream>>>(agg, w2aT, b2a, w2bT, b2b, nullptr,
                                                lw, lb, outp);
}